// Round 6
// baseline (276.073 us; speedup 1.0000x reference)
//
#include <hip/hip_runtime.h>
#include <hip/hip_bf16.h>

// Problem constants
#define BB 2
#define SS 2048
#define DD 1024
#define HH 16
#define DP 64

typedef __bf16 bf16x8 __attribute__((ext_vector_type(8)));
typedef float f32x4 __attribute__((ext_vector_type(4)));

__device__ __forceinline__ unsigned short f2bf(float f) {
  unsigned u = __float_as_uint(f);
  unsigned r = u + 0x7FFFu + ((u >> 16) & 1u);
  return (unsigned short)(r >> 16);
}

__device__ __forceinline__ bf16x8 load8(const unsigned short* p) {
  return __builtin_bit_cast(bf16x8, *(const uint4*)p);
}

__device__ __forceinline__ f32x4 mfma16(bf16x8 a, bf16x8 b, f32x4 c) {
  return __builtin_amdgcn_mfma_f32_16x16x32_bf16(a, b, c, 0, 0, 0);
}

// ---------------- prep: transpose+convert weights, pack mask bits ----------
__global__ __launch_bounds__(256) void imha_prep(
    const float* __restrict__ Wq, const float* __restrict__ Wk,
    const float* __restrict__ Wo, const float* __restrict__ Wv,
    const int* __restrict__ mask,
    unsigned short* __restrict__ wqt, unsigned short* __restrict__ wkt,
    unsigned short* __restrict__ wot, unsigned short* __restrict__ wvt,
    unsigned* __restrict__ mb) {
  const int bx = blockIdx.x, t = threadIdx.x;
  if (bx < 2048) {
    const float* src = (bx < 1024) ? Wq : Wk;
    unsigned short* dst = (bx < 1024) ? wqt : wkt;
    const int tile = bx & 1023;
    const int ty = tile >> 5, tx = tile & 31;
    __shared__ float T[32][33];
    const int r = t >> 3, c4 = (t & 7) * 4;
    const float4 v = *(const float4*)&src[(ty * 32 + r) * 1024 + tx * 32 + c4];
    T[r][c4 + 0] = v.x; T[r][c4 + 1] = v.y; T[r][c4 + 2] = v.z; T[r][c4 + 3] = v.w;
    __syncthreads();
    ushort4 o;
    o.x = f2bf(T[c4 + 0][r]); o.y = f2bf(T[c4 + 1][r]);
    o.z = f2bf(T[c4 + 2][r]); o.w = f2bf(T[c4 + 3][r]);
    *(ushort4*)&dst[(tx * 32 + r) * 1024 + ty * 32 + c4] = o;
  } else if (bx < 2304) {
    const int idx = (bx - 2048) * 256 + t;
    const int n = idx >> 6, k = idx & 63;
    wot[idx] = f2bf(Wo[k * 1024 + n]);
  } else if (bx < 2816) {
    const int widx = (bx - 2304) * 256 + t;  // 131072 words
    const int qr = widx >> 6, wd = widx & 63;
    const int* mrow = mask + qr * 2048 + wd * 32;
    unsigned wv = 0;
    #pragma unroll
    for (int j4 = 0; j4 < 8; ++j4) {
      const int4 m4 = *(const int4*)&mrow[j4 * 4];
      wv |= (unsigned)(m4.x & 1) << (j4 * 4);
      wv |= (unsigned)(m4.y & 1) << (j4 * 4 + 1);
      wv |= (unsigned)(m4.z & 1) << (j4 * 4 + 2);
      wv |= (unsigned)(m4.w & 1) << (j4 * 4 + 3);
    }
    mb[widx] = wv;
  } else {
    const int widx = (bx - 2816) * 256 + t;  // 65536
    const int k = widx >> 6, n = widx & 63;
    wvt[n * 1024 + k] = f2bf(Wv[widx]);
  }
}

// ---------------- projection GEMM (BM=64, BN=128) --------------------------
__global__ __launch_bounds__(256) void imha_proj(
    const float* __restrict__ X, const unsigned short* __restrict__ Wt,
    const float* __restrict__ bias, unsigned short* __restrict__ dst,
    float preScale) {
  __shared__ unsigned short As[64][40];
  __shared__ unsigned short Bs[128][40];
  const int t = threadIdx.x, l = t & 63, w = t >> 6, lr = l & 15, lg = l >> 4;
  const int m0 = blockIdx.x * 64, n0 = blockIdx.y * 128;
  const int wr = w >> 1, wc = w & 1;
  const f32x4 zf = {0.f, 0.f, 0.f, 0.f};
  f32x4 acc[2][4];
  #pragma unroll
  for (int i = 0; i < 2; ++i)
    #pragma unroll
    for (int j = 0; j < 4; ++j) acc[i][j] = zf;

  for (int kk = 0; kk < 32; ++kk) {
    {
      const int rA = t >> 2, cA = (t & 3) * 8;
      const float4 v0 = *(const float4*)&X[(m0 + rA) * 1024 + kk * 32 + cA];
      const float4 v1 = *(const float4*)&X[(m0 + rA) * 1024 + kk * 32 + cA + 4];
      ushort4 o0, o1;
      o0.x = f2bf(v0.x); o0.y = f2bf(v0.y); o0.z = f2bf(v0.z); o0.w = f2bf(v0.w);
      o1.x = f2bf(v1.x); o1.y = f2bf(v1.y); o1.z = f2bf(v1.z); o1.w = f2bf(v1.w);
      *(ushort4*)&As[rA][cA] = o0;
      *(ushort4*)&As[rA][cA + 4] = o1;
      const int rB = t >> 2, cB = (t & 3) * 8;
      #pragma unroll
      for (int p = 0; p < 2; ++p) {
        const uint4 u = *(const uint4*)&Wt[(n0 + p * 64 + rB) * 1024 + kk * 32 + cB];
        *(uint4*)&Bs[p * 64 + rB][cB] = u;
      }
    }
    __syncthreads();
    bf16x8 a[2], bf[4];
    #pragma unroll
    for (int i = 0; i < 2; ++i) a[i] = load8(&As[wr * 32 + i * 16 + lr][lg * 8]);
    #pragma unroll
    for (int j = 0; j < 4; ++j) bf[j] = load8(&Bs[wc * 64 + j * 16 + lr][lg * 8]);
    #pragma unroll
    for (int i = 0; i < 2; ++i)
      #pragma unroll
      for (int j = 0; j < 4; ++j) acc[i][j] = mfma16(a[i], bf[j], acc[i][j]);
    __syncthreads();
  }
  #pragma unroll
  for (int j = 0; j < 4; ++j) {
    const int gn = n0 + wc * 64 + j * 16 + lr;
    const float bv = bias[gn];
    const int h = gn >> 6, d = gn & 63;
    #pragma unroll
    for (int i = 0; i < 2; ++i) {
      #pragma unroll
      for (int r = 0; r < 4; ++r) {
        const int gm = m0 + wr * 32 + i * 16 + lg * 4 + r;
        const int b = gm >> 11, s = gm & 2047;
        dst[(((b * 16 + h) * 2048 + s) << 6) + d] = f2bf((acc[i][j][r] + bv) * preScale);
      }
    }
  }
}

// ---------------- V projection (MFMA, K-split): partials -------------------
__global__ __launch_bounds__(256) void imha_vproj_mm(
    const float* __restrict__ V, const unsigned short* __restrict__ wvt,
    float* __restrict__ ctxvp) {
  const int t = threadIdx.x, l = t & 63, w = t >> 6, lr = l & 15, lg = l >> 4;
  const int m0 = blockIdx.x * 64 + w * 16;
  const int k0 = blockIdx.y * 128;
  const f32x4 zf = {0.f, 0.f, 0.f, 0.f};
  f32x4 acc[4];
  #pragma unroll
  for (int j = 0; j < 4; ++j) acc[j] = zf;
  #pragma unroll
  for (int kk = 0; kk < 4; ++kk) {
    const int kb = k0 + kk * 32 + lg * 8;
    const float4 v0 = *(const float4*)&V[(m0 + lr) * 1024 + kb];
    const float4 v1 = *(const float4*)&V[(m0 + lr) * 1024 + kb + 4];
    union { bf16x8 v; unsigned short u[8]; } au;
    au.u[0] = f2bf(v0.x); au.u[1] = f2bf(v0.y); au.u[2] = f2bf(v0.z); au.u[3] = f2bf(v0.w);
    au.u[4] = f2bf(v1.x); au.u[5] = f2bf(v1.y); au.u[6] = f2bf(v1.z); au.u[7] = f2bf(v1.w);
    #pragma unroll
    for (int j = 0; j < 4; ++j) {
      const bf16x8 bfr = load8(&wvt[(j * 16 + lr) * 1024 + kb]);
      acc[j] = mfma16(au.v, bfr, acc[j]);
    }
  }
  #pragma unroll
  for (int j = 0; j < 4; ++j)
    #pragma unroll
    for (int reg = 0; reg < 4; ++reg) {
      const int m = m0 + lg * 4 + reg;
      ctxvp[((size_t)blockIdx.y * 4096 + m) * 64 + j * 16 + lr] = acc[j][reg];
    }
}

// ---------------- reduce partials -> vpT[b,d,s] bf16 -----------------------
__global__ __launch_bounds__(256) void imha_vred(
    const float* __restrict__ ctxvp, const float* __restrict__ bv,
    unsigned short* __restrict__ vpt) {
  __shared__ float T[128][65];
  const int t = threadIdx.x;
  const int m0 = blockIdx.x * 128;  // 32 blocks
  #pragma unroll
  for (int i = 0; i < 32; ++i) {
    const int e = t + i * 256;
    float s = 0.f;
    #pragma unroll
    for (int p = 0; p < 8; ++p) s += ctxvp[(size_t)p * 262144 + (size_t)m0 * 64 + e];
    T[e >> 6][e & 63] = s;
  }
  __syncthreads();
  const int d = t >> 2, sc = (t & 3) * 32;
  const int b = m0 >> 11, srow = m0 & 2047;
  const float bias = bv[d];
  unsigned short* dst = vpt + ((size_t)b * 64 + d) * 2048 + srow + sc;
  #pragma unroll
  for (int i = 0; i < 32; i += 8) {
    ushort4 o0, o1;
    o0.x = f2bf(T[sc + i + 0][d] + bias); o0.y = f2bf(T[sc + i + 1][d] + bias);
    o0.z = f2bf(T[sc + i + 2][d] + bias); o0.w = f2bf(T[sc + i + 3][d] + bias);
    o1.x = f2bf(T[sc + i + 4][d] + bias); o1.y = f2bf(T[sc + i + 5][d] + bias);
    o1.z = f2bf(T[sc + i + 6][d] + bias); o1.w = f2bf(T[sc + i + 7][d] + bias);
    *(ushort4*)(dst + i) = o0;
    *(ushort4*)(dst + i + 4) = o1;
  }
}

// ---------------- pass1: sum of exp2 over k-tile (K in LDS, 16q/wave) ------
// grid (32,16,4): q0=bx*64 (4 waves x 16q), ks=by, b=bz>>1, 8 heads/block
__global__ __launch_bounds__(256, 4) void imha_pass1(
    const unsigned short* __restrict__ qhb, const unsigned short* __restrict__ khb,
    const unsigned* __restrict__ mb, float* __restrict__ lpart) {
  __shared__ unsigned short Kb[2][8192];  // 2 x 128x64 bf16, XOR-swizzled
  const int t = threadIdx.x, l = t & 63, w = t >> 6, lr = l & 15, lg = l >> 4;
  const int q0 = blockIdx.x * 64, ks = blockIdx.y;
  const int b = blockIdx.z >> 1, hg = blockIdx.z & 1;
  const int k00 = ks * 128;
  const int qw = q0 + w * 16;
  // valid bits: idx = (kt*4+cf)*4+reg, 32 bits
  unsigned vm = 0;
  #pragma unroll
  for (int reg = 0; reg < 4; ++reg) {
    const int qrow = qw + lg * 4 + reg;
    const unsigned* mrow = mb + qrow * 64;
    #pragma unroll
    for (int kt = 0; kt < 2; ++kt)
      #pragma unroll
      for (int cf = 0; cf < 4; ++cf) {
        const unsigned word = mrow[(k00 + kt * 64 + cf * 16) >> 5];
        const unsigned bit = (word >> (((cf & 1) << 4) + lr)) & 1u;
        vm |= (bit ^ 1u) << ((kt * 4 + cf) * 4 + reg);
      }
  }
  const unsigned short* kbase = khb + ((size_t)((b * 16 + hg * 8) * 2048 + k00) << 6);
  uint4 pre[4];
  #pragma unroll
  for (int it = 0; it < 4; ++it)
    pre[it] = *(const uint4*)((const char*)kbase + (it * 256 + t) * 16);
  #pragma unroll
  for (int it = 0; it < 4; ++it) {
    const int off = (it * 256 + t) * 16, row = off >> 7, col = off & 127;
    *(uint4*)((char*)&Kb[0][0] + row * 128 + (col ^ ((row & 7) << 4))) = pre[it];
  }
  __syncthreads();
  #pragma unroll 1
  for (int hh = 0; hh < 8; ++hh) {
    const int h = hg * 8 + hh;
    if (hh < 7) {
      const char* nk = (const char*)(kbase + ((size_t)(hh + 1) << 17));
      #pragma unroll
      for (int it = 0; it < 4; ++it)
        pre[it] = *(const uint4*)(nk + (it * 256 + t) * 16);
    }
    const unsigned short* qb = qhb + ((size_t)((b * 16 + h) * 2048 + qw) << 6);
    const bf16x8 aq0 = load8(qb + ((lr << 6) + lg * 8));
    const bf16x8 aq1 = load8(qb + ((lr << 6) + 32 + lg * 8));
    const char* kl = (const char*)&Kb[hh & 1][0];
    const int sxor = (lr & 7) << 4;
    float lsum[4] = {0.f, 0.f, 0.f, 0.f};
    #pragma unroll
    for (int kt = 0; kt < 2; ++kt) {
      #pragma unroll
      for (int cf = 0; cf < 4; ++cf) {
        const int row = kt * 64 + cf * 16 + lr;
        const bf16x8 b0 = load8((const unsigned short*)(kl + row * 128 + ((lg * 16) ^ sxor)));
        const bf16x8 b1 = load8((const unsigned short*)(kl + row * 128 + ((64 + lg * 16) ^ sxor)));
        const f32x4 zf = {0.f, 0.f, 0.f, 0.f};
        f32x4 acc = mfma16(aq0, b0, zf);
        acc = mfma16(aq1, b1, acc);
        #pragma unroll
        for (int reg = 0; reg < 4; ++reg) {
          const int idx = (kt * 4 + cf) * 4 + reg;
          lsum[reg] += ((vm >> idx) & 1) ? __builtin_exp2f(acc[reg]) : 0.0f;
        }
      }
    }
    if (hh < 7) {
      #pragma unroll
      for (int it = 0; it < 4; ++it) {
        const int off = (it * 256 + t) * 16, row = off >> 7, col = off & 127;
        *(uint4*)((char*)&Kb[(hh + 1) & 1][0] + row * 128 + (col ^ ((row & 7) << 4))) = pre[it];
      }
      __syncthreads();
    }
    #pragma unroll
    for (int reg = 0; reg < 4; ++reg) {
      float s = lsum[reg];
      s += __shfl_xor(s, 1, 16); s += __shfl_xor(s, 2, 16);
      s += __shfl_xor(s, 4, 16); s += __shfl_xor(s, 8, 16);
      if (lr == 0)
        lpart[ks * 65536 + (b * 16 + h) * 2048 + qw + lg * 4 + reg] = s;
    }
  }
}

// ---------------- linv = (1/16) / sum(lpart) -------------------------------
__global__ __launch_bounds__(256) void imha_linv(
    const float* __restrict__ lpart, float* __restrict__ linv) {
  const int i = blockIdx.x * 256 + threadIdx.x;
  float s = 0.f;
  #pragma unroll
  for (int p = 0; p < 16; ++p) s += lpart[p * 65536 + i];
  linv[i] = 0.0625f / s;
}

// ---------------- pass2: attn_mean + partial ctx (K in LDS, 16q/wave) ------
// grid (32,16,2): q0=bx*64 (4 waves x 16q), ksb=by, b=bz
__global__ __launch_bounds__(256, 4) void imha_pass2(
    const unsigned short* __restrict__ qhb, const unsigned short* __restrict__ khb,
    const unsigned short* __restrict__ vpt, const unsigned* __restrict__ mb,
    const float* __restrict__ linv, float* __restrict__ attn_out,
    float* __restrict__ ctxp) {
  __shared__ char smem[32768];  // union: Kb[2][8192] shorts | Ps[64][136] shorts
  unsigned short (*Kb)[8192] = (unsigned short(*)[8192])smem;
  unsigned short (*Ps)[136] = (unsigned short(*)[136])smem;
  const int t = threadIdx.x, l = t & 63, w = t >> 6, lr = l & 15, lg = l >> 4;
  const int q0 = blockIdx.x * 64, ksb = blockIdx.y, b = blockIdx.z;
  const int k00 = ksb * 128;
  const int qw = q0 + w * 16;
  unsigned vm = 0;
  #pragma unroll
  for (int reg = 0; reg < 4; ++reg) {
    const int qrow = qw + lg * 4 + reg;
    const unsigned* mrow = mb + qrow * 64;
    #pragma unroll
    for (int kt = 0; kt < 2; ++kt)
      #pragma unroll
      for (int cf = 0; cf < 4; ++cf) {
        const unsigned word = mrow[(k00 + kt * 64 + cf * 16) >> 5];
        const unsigned bit = (word >> (((cf & 1) << 4) + lr)) & 1u;
        vm |= (bit ^ 1u) << ((kt * 4 + cf) * 4 + reg);
      }
  }
  float pm[2][4][4];
  #pragma unroll
  for (int c = 0; c < 2; ++c)
    #pragma unroll
    for (int d2 = 0; d2 < 4; ++d2)
      #pragma unroll
      for (int e = 0; e < 4; ++e) pm[c][d2][e] = 0.f;

  const unsigned short* kbase = khb + ((size_t)((b * 16) * 2048 + k00) << 6);
  uint4 pre[4];
  #pragma unroll
  for (int it = 0; it < 4; ++it)
    pre[it] = *(const uint4*)((const char*)kbase + (it * 256 + t) * 16);
  #pragma unroll
  for (int it = 0; it < 4; ++it) {
    const int off = (it * 256 + t) * 16, row = off >> 7, col = off & 127;
    *(uint4*)((char*)&Kb[0][0] + row * 128 + (col ^ ((row & 7) << 4))) = pre[it];
  }
  __syncthreads();
  #pragma unroll 1
  for (int h = 0; h < 16; ++h) {
    if (h < 15) {
      const char* nk = (const char*)(kbase + ((size_t)(h + 1) << 17));
      #pragma unroll
      for (int it = 0; it < 4; ++it)
        pre[it] = *(const uint4*)(nk + (it * 256 + t) * 16);
    }
    const unsigned short* qb = qhb + ((size_t)((b * 16 + h) * 2048 + qw) << 6);
    const bf16x8 aq0 = load8(qb + ((lr << 6) + lg * 8));
    const bf16x8 aq1 = load8(qb + ((lr << 6) + 32 + lg * 8));
    const float4 li4 = *(const float4*)&linv[(b * 16 + h) * 2048 + qw + lg * 4];
    const float* lip = (const float*)&li4;
    const char* kl = (const char*)&Kb[h & 1][0];
    const int sxor = (lr & 7) << 4;
    #pragma unroll
    for (int kt = 0; kt < 2; ++kt) {
      #pragma unroll
      for (int cf = 0; cf < 4; ++cf) {
        const int row = kt * 64 + cf * 16 + lr;
        const bf16x8 b0 = load8((const unsigned short*)(kl + row * 128 + ((lg * 16) ^ sxor)));
        const bf16x8 b1 = load8((const unsigned short*)(kl + row * 128 + ((64 + lg * 16) ^ sxor)));
        const f32x4 zf = {0.f, 0.f, 0.f, 0.f};
        f32x4 acc = mfma16(aq0, b0, zf);
        acc = mfma16(aq1, b1, acc);
        #pragma unroll
        for (int reg = 0; reg < 4; ++reg) {
          const int idx = (kt * 4 + cf) * 4 + reg;
          const float e = ((vm >> idx) & 1) ? __builtin_exp2f(acc[reg]) : 0.0f;
          pm[kt][cf][reg] += e * lip[reg];
        }
      }
    }
    if (h < 15) {
      #pragma unroll
      for (int it = 0; it < 4; ++it) {
        const int off = (it * 256 + t) * 16, row = off >> 7, col = off & 127;
        *(uint4*)((char*)&Kb[(h + 1) & 1][0] + row * 128 + (col ^ ((row & 7) << 4))) = pre[it];
      }
      __syncthreads();
    }
  }
  // Kb dead from here; Ps overlays it — barrier so no wave still reads K
  __syncthreads();
  // write attn_mean (f32) + Ps (bf16)
  #pragma unroll
  for (int kt = 0; kt < 2; ++kt)
    #pragma unroll
    for (int cf = 0; cf < 4; ++cf)
      #pragma unroll
      for (int reg = 0; reg < 4; ++reg) {
        const int qrow = qw + lg * 4 + reg;
        const int col = k00 + kt * 64 + cf * 16 + lr;
        const float p = pm[kt][cf][reg];
        attn_out[((size_t)(b * 2048 + qrow) << 11) + col] = p;
        Ps[w * 16 + lg * 4 + reg][kt * 64 + cf * 16 + lr] = f2bf(p);
      }
  // PV: same-wave rows of Ps, V-frags from L2-resident vpt
  const f32x4 zf = {0.f, 0.f, 0.f, 0.f};
  f32x4 ctx[4];
  #pragma unroll
  for (int dcf = 0; dcf < 4; ++dcf) ctx[dcf] = zf;
  #pragma unroll
  for (int k2 = 0; k2 < 4; ++k2) {
    const bf16x8 ap = load8(&Ps[w * 16 + lr][k2 * 32 + lg * 8]);
    #pragma unroll
    for (int dcf = 0; dcf < 4; ++dcf) {
      const bf16x8 bvf = load8(vpt + ((size_t)(b * 64 + dcf * 16 + lr)) * 2048 + k00 + k2 * 32 + lg * 8);
      ctx[dcf] = mfma16(ap, bvf, ctx[dcf]);
    }
  }
  #pragma unroll
  for (int dcf = 0; dcf < 4; ++dcf)
    #pragma unroll
    for (int reg = 0; reg < 4; ++reg) {
      const int m = b * 2048 + qw + lg * 4 + reg;
      ctxp[((size_t)(ksb * 4096 + m) << 6) + dcf * 16 + lr] = ctx[dcf][reg];
    }
}

// ---------------- ctx reduce: ctxr[m][d] bf16 = sum_ks ctxp ----------------
__global__ __launch_bounds__(256) void imha_ctxred(
    const float* __restrict__ ctxp, unsigned short* __restrict__ ctxr) {
  const int i4 = (blockIdx.x * 256 + threadIdx.x) * 4;  // 262144 elems
  float4 s = {0.f, 0.f, 0.f, 0.f};
  #pragma unroll
  for (int p = 0; p < 16; ++p) {
    const float4 v = *(const float4*)&ctxp[(size_t)p * 262144 + i4];
    s.x += v.x; s.y += v.y; s.z += v.z; s.w += v.w;
  }
  ushort4 o;
  o.x = f2bf(s.x); o.y = f2bf(s.y); o.z = f2bf(s.z); o.w = f2bf(s.w);
  *(ushort4*)&ctxr[i4] = o;
}

// ---------------- out projection: out = ctxr @ Wo + bo ---------------------
__global__ __launch_bounds__(256) void imha_outproj(
    const unsigned short* __restrict__ ctxr, const unsigned short* __restrict__ wot,
    const float* __restrict__ bo, float* __restrict__ out) {
  __shared__ unsigned short As[128][72];
  __shared__ unsigned short Bs[128][72];
  const int t = threadIdx.x, l = t & 63, w = t >> 6, lr = l & 15, lg = l >> 4;
  const int m0 = blockIdx.x * 128, n0 = blockIdx.y * 128;
  const int wr = w >> 1, wc = w & 1;
  {
    const int r = t >> 1, cs = (t & 1) * 32;
    #pragma unroll
    for (int i = 0; i < 4; ++i)
      *(uint4*)&As[r][cs + i * 8] = *(const uint4*)&ctxr[(m0 + r) * 64 + cs + i * 8];
    #pragma unroll
    for (int i = 0; i < 4; ++i)
      *(uint4*)&Bs[r][cs + i * 8] = *(const uint4*)&wot[(n0 + r) * 64 + cs + i * 8];
  }
  __syncthreads();
  const f32x4 zf = {0.f, 0.f, 0.f, 0.f};
  f32x4 acc[4][4];
  #pragma unroll
  for (int i = 0; i < 4; ++i)
    #pragma unroll
    for (int j = 0; j < 4; ++j) acc[i][j] = zf;
  #pragma unroll
  for (int k2 = 0; k2 < 2; ++k2) {
    bf16x8 a[4], bb[4];
    #pragma unroll
    for (int i = 0; i < 4; ++i) a[i] = load8(&As[wr * 64 + i * 16 + lr][k2 * 32 + lg * 8]);
    #pragma unroll
    for (int i = 0; i < 4; ++i) bb[i] = load8(&Bs[wc * 64 + i * 16 + lr][k2 * 32 + lg * 8]);
    #pragma unroll
    for (int i = 0; i < 4; ++i)
      #pragma unroll
      for (int j = 0; j < 4; ++j) acc[i][j] = mfma16(a[i], bb[j], acc[i][j]);
  }
  #pragma unroll
  for (int j = 0; j < 4; ++j) {
    const int gn = n0 + wc * 64 + j * 16 + lr;
    const float bv = bo[gn];
    #pragma unroll
    for (int i = 0; i < 4; ++i) {
      #pragma unroll
      for (int r = 0; r < 4; ++r) {
        const int gm = m0 + wr * 64 + i * 16 + lg * 4 + r;
        out[((size_t)gm << 10) + gn] = acc[i][j][r] + bv;
      }
    }
  }
}

// ---------------- host launch ----------------------------------------------
extern "C" void kernel_launch(void* const* d_in, const int* in_sizes, int n_in,
                              void* d_out, int out_size, void* d_ws, size_t ws_size,
                              hipStream_t stream) {
  const float* q  = (const float*)d_in[0];
  const float* k  = (const float*)d_in[1];
  const float* v  = (const float*)d_in[2];
  const int*  mask = (const int*)d_in[3];
  const float* Wq = (const float*)d_in[4];
  const float* bq = (const float*)d_in[5];
  const float* Wk = (const float*)d_in[6];
  const float* bk = (const float*)d_in[7];
  const float* Wv = (const float*)d_in[8];
  const float* bv = (const float*)d_in[9];
  const float* Wo = (const float*)d_in[10];
  const float* bo = (const float*)d_in[11];

  char* ws = (char*)d_ws;
  unsigned short* wqt  = (unsigned short*)(ws + 0);          // 2 MB
  unsigned short* wkt  = (unsigned short*)(ws + 2097152);    // 2 MB
  unsigned short* wot  = (unsigned short*)(ws + 4194304);    // 128 KB
  unsigned*       mb   = (unsigned*)      (ws + 4325376);    // 512 KB
  unsigned short* qhb  = (unsigned short*)(ws + 4849664);    // 8 MB
  unsigned short* khb  = (unsigned short*)(ws + 13238272);   // 8 MB
  unsigned short* vpt  = (unsigned short*)(ws + 21626880);   // 512 KB
  float*          linv = (float*)         (ws + 22151168);   // 256 KB
  float*          ctxp = (float*)         (ws + 22413312);   // 16 MB -> ends 39190528
  unsigned short* ctxr = (unsigned short*)(ws + 39190528);   // 512 KB -> ends 39702528
  // aliases inside ctxp region (dead at time of use):
  unsigned short* wvt  = (unsigned short*)(ws + 22413312);             // 128 KB, dead after vproj_mm
  float*          ctxvp= (float*)         (ws + 22413312 + 131072);    // 8 MB, dead after vred
  float*          lpart= (float*)         (ws + 22413312);             // 4 MB, dead before pass2

  float* out  = (float*)d_out;
  float* attn = out + (size_t)BB * SS * DD;  // 4,194,304

  const float qScale = 0.125f * 1.44269504088896340736f;  // fold log2(e) for exp2

  imha_prep<<<3072, 256, 0, stream>>>(Wq, Wk, Wo, Wv, mask, wqt, wkt, wot, wvt, mb);
  imha_vproj_mm<<<dim3(64, 8), 256, 0, stream>>>(v, wvt, ctxvp);
  imha_vred<<<32, 256, 0, stream>>>(ctxvp, bv, vpt);
  imha_proj<<<dim3(64, 8), 256, 0, stream>>>(q, wqt, bq, qhb, qScale);
  imha_proj<<<dim3(64, 8), 256, 0, stream>>>(k, wkt, bk, khb, 1.0f);
  imha_pass1<<<dim3(32, 16, 4), 256, 0, stream>>>(qhb, khb, mb, lpart);
  imha_linv<<<256, 256, 0, stream>>>(lpart, linv);
  imha_pass2<<<dim3(32, 16, 2), 256, 0, stream>>>(qhb, khb, vpt, mb, linv, attn, ctxp);
  imha_ctxred<<<256, 256, 0, stream>>>(ctxp, ctxr);
  imha_outproj<<<dim3(32, 8), 256, 0, stream>>>(ctxr, wot, bo, out);
}

// Round 7
// 241.515 us; speedup vs baseline: 1.1431x; 1.1431x over previous
//
#include <hip/hip_runtime.h>
#include <hip/hip_bf16.h>

// Problem constants
#define BB 2
#define SS 2048
#define DD 1024
#define HH 16
#define DP 64

typedef __bf16 bf16x8 __attribute__((ext_vector_type(8)));
typedef float f32x4 __attribute__((ext_vector_type(4)));

__device__ __forceinline__ unsigned short f2bf(float f) {
  unsigned u = __float_as_uint(f);
  unsigned r = u + 0x7FFFu + ((u >> 16) & 1u);
  return (unsigned short)(r >> 16);
}

__device__ __forceinline__ bf16x8 load8(const unsigned short* p) {
  return __builtin_bit_cast(bf16x8, *(const uint4*)p);
}

__device__ __forceinline__ f32x4 mfma16(bf16x8 a, bf16x8 b, f32x4 c) {
  return __builtin_amdgcn_mfma_f32_16x16x32_bf16(a, b, c, 0, 0, 0);
}

// ---------------- prep: transpose+convert weights, pack mask bits ----------
__global__ __launch_bounds__(256) void imha_prep(
    const float* __restrict__ Wq, const float* __restrict__ Wk,
    const float* __restrict__ Wo, const float* __restrict__ Wv,
    const int* __restrict__ mask,
    unsigned short* __restrict__ wqt, unsigned short* __restrict__ wkt,
    unsigned short* __restrict__ wot, unsigned short* __restrict__ wvt,
    unsigned* __restrict__ mb) {
  const int bx = blockIdx.x, t = threadIdx.x;
  if (bx < 2048) {
    const float* src = (bx < 1024) ? Wq : Wk;
    unsigned short* dst = (bx < 1024) ? wqt : wkt;
    const int tile = bx & 1023;
    const int ty = tile >> 5, tx = tile & 31;
    __shared__ float T[32][33];
    const int r = t >> 3, c4 = (t & 7) * 4;
    const float4 v = *(const float4*)&src[(ty * 32 + r) * 1024 + tx * 32 + c4];
    T[r][c4 + 0] = v.x; T[r][c4 + 1] = v.y; T[r][c4 + 2] = v.z; T[r][c4 + 3] = v.w;
    __syncthreads();
    ushort4 o;
    o.x = f2bf(T[c4 + 0][r]); o.y = f2bf(T[c4 + 1][r]);
    o.z = f2bf(T[c4 + 2][r]); o.w = f2bf(T[c4 + 3][r]);
    *(ushort4*)&dst[(tx * 32 + r) * 1024 + ty * 32 + c4] = o;
  } else if (bx < 2304) {
    const int idx = (bx - 2048) * 256 + t;
    const int n = idx >> 6, k = idx & 63;
    wot[idx] = f2bf(Wo[k * 1024 + n]);
  } else if (bx < 2816) {
    const int widx = (bx - 2304) * 256 + t;  // 131072 words
    const int qr = widx >> 6, wd = widx & 63;
    const int* mrow = mask + qr * 2048 + wd * 32;
    unsigned wv = 0;
    #pragma unroll
    for (int j4 = 0; j4 < 8; ++j4) {
      const int4 m4 = *(const int4*)&mrow[j4 * 4];
      wv |= (unsigned)(m4.x & 1) << (j4 * 4);
      wv |= (unsigned)(m4.y & 1) << (j4 * 4 + 1);
      wv |= (unsigned)(m4.z & 1) << (j4 * 4 + 2);
      wv |= (unsigned)(m4.w & 1) << (j4 * 4 + 3);
    }
    mb[widx] = wv;
  } else {
    const int widx = (bx - 2816) * 256 + t;  // 65536
    const int k = widx >> 6, n = widx & 63;
    wvt[n * 1024 + k] = f2bf(Wv[widx]);
  }
}

// ---------------- projection GEMM (BM=64, BN=128) --------------------------
__global__ __launch_bounds__(256) void imha_proj(
    const float* __restrict__ X, const unsigned short* __restrict__ Wt,
    const float* __restrict__ bias, unsigned short* __restrict__ dst,
    float preScale) {
  __shared__ unsigned short As[64][40];
  __shared__ unsigned short Bs[128][40];
  const int t = threadIdx.x, l = t & 63, w = t >> 6, lr = l & 15, lg = l >> 4;
  const int m0 = blockIdx.x * 64, n0 = blockIdx.y * 128;
  const int wr = w >> 1, wc = w & 1;
  const f32x4 zf = {0.f, 0.f, 0.f, 0.f};
  f32x4 acc[2][4];
  #pragma unroll
  for (int i = 0; i < 2; ++i)
    #pragma unroll
    for (int j = 0; j < 4; ++j) acc[i][j] = zf;

  for (int kk = 0; kk < 32; ++kk) {
    {
      const int rA = t >> 2, cA = (t & 3) * 8;
      const float4 v0 = *(const float4*)&X[(m0 + rA) * 1024 + kk * 32 + cA];
      const float4 v1 = *(const float4*)&X[(m0 + rA) * 1024 + kk * 32 + cA + 4];
      ushort4 o0, o1;
      o0.x = f2bf(v0.x); o0.y = f2bf(v0.y); o0.z = f2bf(v0.z); o0.w = f2bf(v0.w);
      o1.x = f2bf(v1.x); o1.y = f2bf(v1.y); o1.z = f2bf(v1.z); o1.w = f2bf(v1.w);
      *(ushort4*)&As[rA][cA] = o0;
      *(ushort4*)&As[rA][cA + 4] = o1;
      const int rB = t >> 2, cB = (t & 3) * 8;
      #pragma unroll
      for (int p = 0; p < 2; ++p) {
        const uint4 u = *(const uint4*)&Wt[(n0 + p * 64 + rB) * 1024 + kk * 32 + cB];
        *(uint4*)&Bs[p * 64 + rB][cB] = u;
      }
    }
    __syncthreads();
    bf16x8 a[2], bf[4];
    #pragma unroll
    for (int i = 0; i < 2; ++i) a[i] = load8(&As[wr * 32 + i * 16 + lr][lg * 8]);
    #pragma unroll
    for (int j = 0; j < 4; ++j) bf[j] = load8(&Bs[wc * 64 + j * 16 + lr][lg * 8]);
    #pragma unroll
    for (int i = 0; i < 2; ++i)
      #pragma unroll
      for (int j = 0; j < 4; ++j) acc[i][j] = mfma16(a[i], bf[j], acc[i][j]);
    __syncthreads();
  }
  #pragma unroll
  for (int j = 0; j < 4; ++j) {
    const int gn = n0 + wc * 64 + j * 16 + lr;
    const float bv = bias[gn];
    const int h = gn >> 6, d = gn & 63;
    #pragma unroll
    for (int i = 0; i < 2; ++i) {
      #pragma unroll
      for (int r = 0; r < 4; ++r) {
        const int gm = m0 + wr * 32 + i * 16 + lg * 4 + r;
        const int b = gm >> 11, s = gm & 2047;
        dst[(((b * 16 + h) * 2048 + s) << 6) + d] = f2bf((acc[i][j][r] + bv) * preScale);
      }
    }
  }
}

// ---------------- V projection (MFMA, K-split): partials -------------------
__global__ __launch_bounds__(256) void imha_vproj_mm(
    const float* __restrict__ V, const unsigned short* __restrict__ wvt,
    float* __restrict__ ctxvp) {
  const int t = threadIdx.x, l = t & 63, w = t >> 6, lr = l & 15, lg = l >> 4;
  const int m0 = blockIdx.x * 64 + w * 16;
  const int k0 = blockIdx.y * 128;
  const f32x4 zf = {0.f, 0.f, 0.f, 0.f};
  f32x4 acc[4];
  #pragma unroll
  for (int j = 0; j < 4; ++j) acc[j] = zf;
  #pragma unroll
  for (int kk = 0; kk < 4; ++kk) {
    const int kb = k0 + kk * 32 + lg * 8;
    const float4 v0 = *(const float4*)&V[(m0 + lr) * 1024 + kb];
    const float4 v1 = *(const float4*)&V[(m0 + lr) * 1024 + kb + 4];
    union { bf16x8 v; unsigned short u[8]; } au;
    au.u[0] = f2bf(v0.x); au.u[1] = f2bf(v0.y); au.u[2] = f2bf(v0.z); au.u[3] = f2bf(v0.w);
    au.u[4] = f2bf(v1.x); au.u[5] = f2bf(v1.y); au.u[6] = f2bf(v1.z); au.u[7] = f2bf(v1.w);
    #pragma unroll
    for (int j = 0; j < 4; ++j) {
      const bf16x8 bfr = load8(&wvt[(j * 16 + lr) * 1024 + kb]);
      acc[j] = mfma16(au.v, bfr, acc[j]);
    }
  }
  #pragma unroll
  for (int j = 0; j < 4; ++j)
    #pragma unroll
    for (int reg = 0; reg < 4; ++reg) {
      const int m = m0 + lg * 4 + reg;
      ctxvp[((size_t)blockIdx.y * 4096 + m) * 64 + j * 16 + lr] = acc[j][reg];
    }
}

// ---------------- reduce partials -> vpT[b,d,s] bf16 -----------------------
__global__ __launch_bounds__(256) void imha_vred(
    const float* __restrict__ ctxvp, const float* __restrict__ bv,
    unsigned short* __restrict__ vpt) {
  __shared__ float T[128][65];
  const int t = threadIdx.x;
  const int m0 = blockIdx.x * 128;  // 32 blocks
  #pragma unroll
  for (int i = 0; i < 32; ++i) {
    const int e = t + i * 256;
    float s = 0.f;
    #pragma unroll
    for (int p = 0; p < 8; ++p) s += ctxvp[(size_t)p * 262144 + (size_t)m0 * 64 + e];
    T[e >> 6][e & 63] = s;
  }
  __syncthreads();
  const int d = t >> 2, sc = (t & 3) * 32;
  const int b = m0 >> 11, srow = m0 & 2047;
  const float bias = bv[d];
  unsigned short* dst = vpt + ((size_t)b * 64 + d) * 2048 + srow + sc;
  #pragma unroll
  for (int i = 0; i < 32; i += 8) {
    ushort4 o0, o1;
    o0.x = f2bf(T[sc + i + 0][d] + bias); o0.y = f2bf(T[sc + i + 1][d] + bias);
    o0.z = f2bf(T[sc + i + 2][d] + bias); o0.w = f2bf(T[sc + i + 3][d] + bias);
    o1.x = f2bf(T[sc + i + 4][d] + bias); o1.y = f2bf(T[sc + i + 5][d] + bias);
    o1.z = f2bf(T[sc + i + 6][d] + bias); o1.w = f2bf(T[sc + i + 7][d] + bias);
    *(ushort4*)(dst + i) = o0;
    *(ushort4*)(dst + i + 4) = o1;
  }
}

// ---------------- pass1: sum of exp2 over k-tile (K in LDS) ----------------
// grid (16,16,4): q0=bx*128 (4 waves x 32q), ks=by, b=bz>>1, 8 heads/block
// mask folded into MFMA accumulator init (aini): no per-logit select.
__global__ __launch_bounds__(256, 3) void imha_pass1(
    const unsigned short* __restrict__ qhb, const unsigned short* __restrict__ khb,
    const unsigned* __restrict__ mb, float* __restrict__ lpart) {
  __shared__ unsigned short Kb[2][8192];  // 2 x 128x64 bf16, XOR-swizzled
  const int t = threadIdx.x, l = t & 63, w = t >> 6, lr = l & 15, lg = l >> 4;
  const int q0 = blockIdx.x * 128, ks = blockIdx.y;
  const int b = blockIdx.z >> 1, hg = blockIdx.z & 1;
  const int k00 = ks * 128;
  const int qw = q0 + w * 32;
  // accumulator-init mask bias: head-independent, computed once
  f32x4 aini[2][2][4];  // [rf][kt][cf], lanes give reg
  #pragma unroll
  for (int rf = 0; rf < 2; ++rf)
    #pragma unroll
    for (int reg = 0; reg < 4; ++reg) {
      const int qrow = qw + rf * 16 + lg * 4 + reg;
      const unsigned* mrow = mb + qrow * 64;
      #pragma unroll
      for (int kt = 0; kt < 2; ++kt)
        #pragma unroll
        for (int cf = 0; cf < 4; ++cf) {
          const unsigned word = mrow[(k00 + kt * 64 + cf * 16) >> 5];
          const unsigned bit = (word >> (((cf & 1) << 4) + lr)) & 1u;
          aini[rf][kt][cf][reg] = bit ? -30000.0f : 0.0f;
        }
    }
  const unsigned short* kbase = khb + ((size_t)((b * 16 + hg * 8) * 2048 + k00) << 6);
  uint4 pre[4];
  #pragma unroll
  for (int it = 0; it < 4; ++it)
    pre[it] = *(const uint4*)((const char*)kbase + (it * 256 + t) * 16);
  #pragma unroll
  for (int it = 0; it < 4; ++it) {
    const int off = (it * 256 + t) * 16, row = off >> 7, col = off & 127;
    *(uint4*)((char*)&Kb[0][0] + row * 128 + (col ^ ((row & 7) << 4))) = pre[it];
  }
  __syncthreads();
  #pragma unroll 1
  for (int hh = 0; hh < 8; ++hh) {
    const int h = hg * 8 + hh;
    if (hh < 7) {
      const char* nk = (const char*)(kbase + ((size_t)(hh + 1) << 17));
      #pragma unroll
      for (int it = 0; it < 4; ++it)
        pre[it] = *(const uint4*)(nk + (it * 256 + t) * 16);
    }
    const unsigned short* qb = qhb + ((size_t)((b * 16 + h) * 2048 + qw) << 6);
    bf16x8 aq[2][2];
    #pragma unroll
    for (int rf = 0; rf < 2; ++rf)
      #pragma unroll
      for (int k2 = 0; k2 < 2; ++k2)
        aq[rf][k2] = load8(qb + (((rf * 16 + lr) << 6) + k2 * 32 + lg * 8));
    const char* kl = (const char*)&Kb[hh & 1][0];
    const int sxor = (lr & 7) << 4;
    float lsum[2][4] = {0.f, 0.f, 0.f, 0.f, 0.f, 0.f, 0.f, 0.f};
    #pragma unroll
    for (int kt = 0; kt < 2; ++kt) {
      #pragma unroll
      for (int cf = 0; cf < 4; ++cf) {
        const int row = kt * 64 + cf * 16 + lr;
        const bf16x8 b0 = load8((const unsigned short*)(kl + row * 128 + ((lg * 16) ^ sxor)));
        const bf16x8 b1 = load8((const unsigned short*)(kl + row * 128 + ((64 + lg * 16) ^ sxor)));
        #pragma unroll
        for (int rf = 0; rf < 2; ++rf) {
          f32x4 acc = mfma16(aq[rf][0], b0, aini[rf][kt][cf]);
          acc = mfma16(aq[rf][1], b1, acc);
          #pragma unroll
          for (int reg = 0; reg < 4; ++reg)
            lsum[rf][reg] += __builtin_exp2f(acc[reg]);
        }
      }
    }
    if (hh < 7) {
      #pragma unroll
      for (int it = 0; it < 4; ++it) {
        const int off = (it * 256 + t) * 16, row = off >> 7, col = off & 127;
        *(uint4*)((char*)&Kb[(hh + 1) & 1][0] + row * 128 + (col ^ ((row & 7) << 4))) = pre[it];
      }
      __syncthreads();
    }
    #pragma unroll
    for (int rf = 0; rf < 2; ++rf)
      #pragma unroll
      for (int reg = 0; reg < 4; ++reg) {
        float s = lsum[rf][reg];
        s += __shfl_xor(s, 1, 16); s += __shfl_xor(s, 2, 16);
        s += __shfl_xor(s, 4, 16); s += __shfl_xor(s, 8, 16);
        if (lr == 0)
          lpart[ks * 65536 + (b * 16 + h) * 2048 + qw + rf * 16 + lg * 4 + reg] = s;
      }
  }
}

// ---------------- linv = (1/16) / sum(lpart) -------------------------------
__global__ __launch_bounds__(256) void imha_linv(
    const float* __restrict__ lpart, float* __restrict__ linv) {
  const int i = blockIdx.x * 256 + threadIdx.x;
  float s = 0.f;
  #pragma unroll
  for (int p = 0; p < 16; ++p) s += lpart[p * 65536 + i];
  linv[i] = 0.0625f / s;
}

// ---------------- pass2: attn_mean + partial ctx (K in LDS) ----------------
// grid (16,16,2): q-tile 128 (4 waves x 32q), k-tile 128, h-loop 16
__global__ __launch_bounds__(256, 2) void imha_pass2(
    const unsigned short* __restrict__ qhb, const unsigned short* __restrict__ khb,
    const unsigned short* __restrict__ vpt, const unsigned* __restrict__ mb,
    const float* __restrict__ linv, float* __restrict__ attn_out,
    float* __restrict__ ctxp) {
  __shared__ unsigned short Ps[128][136];
  __shared__ unsigned short Kb[2][8192];
  const int t = threadIdx.x, l = t & 63, w = t >> 6, lr = l & 15, lg = l >> 4;
  const int q0 = blockIdx.x * 128, ksb = blockIdx.y, b = blockIdx.z;
  const int k00 = ksb * 128;
  const int qw = q0 + w * 32;
  f32x4 aini[2][2][4];
  #pragma unroll
  for (int rf = 0; rf < 2; ++rf)
    #pragma unroll
    for (int reg = 0; reg < 4; ++reg) {
      const int qrow = qw + rf * 16 + lg * 4 + reg;
      const unsigned* mrow = mb + qrow * 64;
      #pragma unroll
      for (int kt = 0; kt < 2; ++kt)
        #pragma unroll
        for (int cf = 0; cf < 4; ++cf) {
          const unsigned word = mrow[(k00 + kt * 64 + cf * 16) >> 5];
          const unsigned bit = (word >> (((cf & 1) << 4) + lr)) & 1u;
          aini[rf][kt][cf][reg] = bit ? -30000.0f : 0.0f;
        }
    }
  float pm[2][2][4][4];
  #pragma unroll
  for (int a = 0; a < 2; ++a)
    #pragma unroll
    for (int c = 0; c < 2; ++c)
      #pragma unroll
      for (int d2 = 0; d2 < 4; ++d2)
        #pragma unroll
        for (int e = 0; e < 4; ++e) pm[a][c][d2][e] = 0.f;

  const unsigned short* kbase = khb + ((size_t)((b * 16) * 2048 + k00) << 6);
  uint4 pre[4];
  #pragma unroll
  for (int it = 0; it < 4; ++it)
    pre[it] = *(const uint4*)((const char*)kbase + (it * 256 + t) * 16);
  #pragma unroll
  for (int it = 0; it < 4; ++it) {
    const int off = (it * 256 + t) * 16, row = off >> 7, col = off & 127;
    *(uint4*)((char*)&Kb[0][0] + row * 128 + (col ^ ((row & 7) << 4))) = pre[it];
  }
  __syncthreads();
  #pragma unroll 1
  for (int h = 0; h < 16; ++h) {
    if (h < 15) {
      const char* nk = (const char*)(kbase + ((size_t)(h + 1) << 17));
      #pragma unroll
      for (int it = 0; it < 4; ++it)
        pre[it] = *(const uint4*)(nk + (it * 256 + t) * 16);
    }
    const unsigned short* qb = qhb + ((size_t)((b * 16 + h) * 2048 + qw) << 6);
    bf16x8 aq[2][2];
    #pragma unroll
    for (int rf = 0; rf < 2; ++rf)
      #pragma unroll
      for (int k2 = 0; k2 < 2; ++k2)
        aq[rf][k2] = load8(qb + (((rf * 16 + lr) << 6) + k2 * 32 + lg * 8));
    float4 li4[2];
    #pragma unroll
    for (int rf = 0; rf < 2; ++rf)
      li4[rf] = *(const float4*)&linv[(b * 16 + h) * 2048 + qw + rf * 16 + lg * 4];
    const char* kl = (const char*)&Kb[h & 1][0];
    const int sxor = (lr & 7) << 4;
    #pragma unroll
    for (int kt = 0; kt < 2; ++kt) {
      #pragma unroll
      for (int cf = 0; cf < 4; ++cf) {
        const int row = kt * 64 + cf * 16 + lr;
        const bf16x8 b0 = load8((const unsigned short*)(kl + row * 128 + ((lg * 16) ^ sxor)));
        const bf16x8 b1 = load8((const unsigned short*)(kl + row * 128 + ((64 + lg * 16) ^ sxor)));
        #pragma unroll
        for (int rf = 0; rf < 2; ++rf) {
          f32x4 acc = mfma16(aq[rf][0], b0, aini[rf][kt][cf]);
          acc = mfma16(aq[rf][1], b1, acc);
          const float* lip = (const float*)&li4[rf];
          #pragma unroll
          for (int reg = 0; reg < 4; ++reg)
            pm[rf][kt][cf][reg] += __builtin_exp2f(acc[reg]) * lip[reg];
        }
      }
    }
    if (h < 15) {
      #pragma unroll
      for (int it = 0; it < 4; ++it) {
        const int off = (it * 256 + t) * 16, row = off >> 7, col = off & 127;
        *(uint4*)((char*)&Kb[(h + 1) & 1][0] + row * 128 + (col ^ ((row & 7) << 4))) = pre[it];
      }
      __syncthreads();
    }
  }
  // write attn_mean (f32) + Ps (bf16)
  #pragma unroll
  for (int rf = 0; rf < 2; ++rf)
    #pragma unroll
    for (int kt = 0; kt < 2; ++kt)
      #pragma unroll
      for (int cf = 0; cf < 4; ++cf)
        #pragma unroll
        for (int reg = 0; reg < 4; ++reg) {
          const int qrow = qw + rf * 16 + lg * 4 + reg;
          const int col = k00 + kt * 64 + cf * 16 + lr;
          const float p = pm[rf][kt][cf][reg];
          attn_out[((size_t)(b * 2048 + qrow) << 11) + col] = p;
          Ps[w * 32 + rf * 16 + lg * 4 + reg][kt * 64 + cf * 16 + lr] = f2bf(p);
        }
  // PV: same-wave rows of Ps, V-frags from L2-resident vpt
  const f32x4 zf = {0.f, 0.f, 0.f, 0.f};
  f32x4 ctx[2][4];
  #pragma unroll
  for (int rf = 0; rf < 2; ++rf)
    #pragma unroll
    for (int dcf = 0; dcf < 4; ++dcf) ctx[rf][dcf] = zf;
  #pragma unroll
  for (int k2 = 0; k2 < 4; ++k2) {
    bf16x8 ap[2];
    #pragma unroll
    for (int rf = 0; rf < 2; ++rf)
      ap[rf] = load8(&Ps[w * 32 + rf * 16 + lr][k2 * 32 + lg * 8]);
    #pragma unroll
    for (int dcf = 0; dcf < 4; ++dcf) {
      const bf16x8 bvf = load8(vpt + ((size_t)(b * 64 + dcf * 16 + lr)) * 2048 + k00 + k2 * 32 + lg * 8);
      #pragma unroll
      for (int rf = 0; rf < 2; ++rf) ctx[rf][dcf] = mfma16(ap[rf], bvf, ctx[rf][dcf]);
    }
  }
  #pragma unroll
  for (int rf = 0; rf < 2; ++rf)
    #pragma unroll
    for (int dcf = 0; dcf < 4; ++dcf)
      #pragma unroll
      for (int reg = 0; reg < 4; ++reg) {
        const int m = b * 2048 + qw + rf * 16 + lg * 4 + reg;
        ctxp[((size_t)(ksb * 4096 + m) << 6) + dcf * 16 + lr] = ctx[rf][dcf][reg];
      }
}

// ---------------- ctx reduce: ctxr[m][d] bf16 = sum_ks ctxp ----------------
__global__ __launch_bounds__(256) void imha_ctxred(
    const float* __restrict__ ctxp, unsigned short* __restrict__ ctxr) {
  const int i4 = (blockIdx.x * 256 + threadIdx.x) * 4;  // 262144 elems
  float4 s = {0.f, 0.f, 0.f, 0.f};
  #pragma unroll
  for (int p = 0; p < 16; ++p) {
    const float4 v = *(const float4*)&ctxp[(size_t)p * 262144 + i4];
    s.x += v.x; s.y += v.y; s.z += v.z; s.w += v.w;
  }
  ushort4 o;
  o.x = f2bf(s.x); o.y = f2bf(s.y); o.z = f2bf(s.z); o.w = f2bf(s.w);
  *(ushort4*)&ctxr[i4] = o;
}

// ---------------- out projection: out = ctxr @ Wo + bo ---------------------
__global__ __launch_bounds__(256) void imha_outproj(
    const unsigned short* __restrict__ ctxr, const unsigned short* __restrict__ wot,
    const float* __restrict__ bo, float* __restrict__ out) {
  __shared__ unsigned short As[128][72];
  __shared__ unsigned short Bs[128][72];
  const int t = threadIdx.x, l = t & 63, w = t >> 6, lr = l & 15, lg = l >> 4;
  const int m0 = blockIdx.x * 128, n0 = blockIdx.y * 128;
  const int wr = w >> 1, wc = w & 1;
  {
    const int r = t >> 1, cs = (t & 1) * 32;
    #pragma unroll
    for (int i = 0; i < 4; ++i)
      *(uint4*)&As[r][cs + i * 8] = *(const uint4*)&ctxr[(m0 + r) * 64 + cs + i * 8];
    #pragma unroll
    for (int i = 0; i < 4; ++i)
      *(uint4*)&Bs[r][cs + i * 8] = *(const uint4*)&wot[(n0 + r) * 64 + cs + i * 8];
  }
  __syncthreads();
  const f32x4 zf = {0.f, 0.f, 0.f, 0.f};
  f32x4 acc[4][4];
  #pragma unroll
  for (int i = 0; i < 4; ++i)
    #pragma unroll
    for (int j = 0; j < 4; ++j) acc[i][j] = zf;
  #pragma unroll
  for (int k2 = 0; k2 < 2; ++k2) {
    bf16x8 a[4], bb[4];
    #pragma unroll
    for (int i = 0; i < 4; ++i) a[i] = load8(&As[wr * 64 + i * 16 + lr][k2 * 32 + lg * 8]);
    #pragma unroll
    for (int i = 0; i < 4; ++i) bb[i] = load8(&Bs[wc * 64 + i * 16 + lr][k2 * 32 + lg * 8]);
    #pragma unroll
    for (int i = 0; i < 4; ++i)
      #pragma unroll
      for (int j = 0; j < 4; ++j) acc[i][j] = mfma16(a[i], bb[j], acc[i][j]);
  }
  #pragma unroll
  for (int j = 0; j < 4; ++j) {
    const int gn = n0 + wc * 64 + j * 16 + lr;
    const float bv = bo[gn];
    #pragma unroll
    for (int i = 0; i < 4; ++i) {
      #pragma unroll
      for (int r = 0; r < 4; ++r) {
        const int gm = m0 + wr * 64 + i * 16 + lg * 4 + r;
        out[((size_t)gm << 10) + gn] = acc[i][j][r] + bv;
      }
    }
  }
}

// ---------------- host launch ----------------------------------------------
extern "C" void kernel_launch(void* const* d_in, const int* in_sizes, int n_in,
                              void* d_out, int out_size, void* d_ws, size_t ws_size,
                              hipStream_t stream) {
  const float* q  = (const float*)d_in[0];
  const float* k  = (const float*)d_in[1];
  const float* v  = (const float*)d_in[2];
  const int*  mask = (const int*)d_in[3];
  const float* Wq = (const float*)d_in[4];
  const float* bq = (const float*)d_in[5];
  const float* Wk = (const float*)d_in[6];
  const float* bk = (const float*)d_in[7];
  const float* Wv = (const float*)d_in[8];
  const float* bv = (const float*)d_in[9];
  const float* Wo = (const float*)d_in[10];
  const float* bo = (const float*)d_in[11];

  char* ws = (char*)d_ws;
  unsigned short* wqt  = (unsigned short*)(ws + 0);          // 2 MB
  unsigned short* wkt  = (unsigned short*)(ws + 2097152);    // 2 MB
  unsigned short* wot  = (unsigned short*)(ws + 4194304);    // 128 KB
  unsigned*       mb   = (unsigned*)      (ws + 4325376);    // 512 KB
  unsigned short* qhb  = (unsigned short*)(ws + 4849664);    // 8 MB
  unsigned short* khb  = (unsigned short*)(ws + 13238272);   // 8 MB
  unsigned short* vpt  = (unsigned short*)(ws + 21626880);   // 512 KB
  float*          linv = (float*)         (ws + 22151168);   // 256 KB
  float*          ctxp = (float*)         (ws + 22413312);   // 16 MB -> ends 39190528
  unsigned short* ctxr = (unsigned short*)(ws + 39190528);   // 512 KB -> ends 39702528
  // aliases inside ctxp region (dead at time of use):
  unsigned short* wvt  = (unsigned short*)(ws + 22413312);             // 128 KB, dead after vproj_mm
  float*          ctxvp= (float*)         (ws + 22413312 + 131072);    // 8 MB, dead after vred
  float*          lpart= (float*)         (ws + 22413312);             // 4 MB, dead before pass2

  float* out  = (float*)d_out;
  float* attn = out + (size_t)BB * SS * DD;  // 4,194,304

  const float qScale = 0.125f * 1.44269504088896340736f;  // fold log2(e) for exp2

  imha_prep<<<3072, 256, 0, stream>>>(Wq, Wk, Wo, Wv, mask, wqt, wkt, wot, wvt, mb);
  imha_vproj_mm<<<dim3(64, 8), 256, 0, stream>>>(v, wvt, ctxvp);
  imha_vred<<<32, 256, 0, stream>>>(ctxvp, bv, vpt);
  imha_proj<<<dim3(64, 8), 256, 0, stream>>>(q, wqt, bq, qhb, qScale);
  imha_proj<<<dim3(64, 8), 256, 0, stream>>>(k, wkt, bk, khb, 1.0f);
  imha_pass1<<<dim3(16, 16, 4), 256, 0, stream>>>(qhb, khb, mb, lpart);
  imha_linv<<<256, 256, 0, stream>>>(lpart, linv);
  imha_pass2<<<dim3(16, 16, 2), 256, 0, stream>>>(qhb, khb, vpt, mb, linv, attn, ctxp);
  imha_ctxred<<<256, 256, 0, stream>>>(ctxp, ctxr);
  imha_outproj<<<dim3(32, 8), 256, 0, stream>>>(ctxr, wot, bo, out);
}

// Round 8
// 220.966 us; speedup vs baseline: 1.2494x; 1.0930x over previous
//
#include <hip/hip_runtime.h>
#include <hip/hip_bf16.h>

// Problem constants
#define BB 2
#define SS 2048
#define DD 1024
#define HH 16
#define DP 64

typedef __bf16 bf16x8 __attribute__((ext_vector_type(8)));
typedef float f32x4 __attribute__((ext_vector_type(4)));

__device__ __forceinline__ unsigned short f2bf(float f) {
  unsigned u = __float_as_uint(f);
  unsigned r = u + 0x7FFFu + ((u >> 16) & 1u);
  return (unsigned short)(r >> 16);
}

__device__ __forceinline__ bf16x8 load8(const unsigned short* p) {
  return __builtin_bit_cast(bf16x8, *(const uint4*)p);
}

__device__ __forceinline__ f32x4 mfma16(bf16x8 a, bf16x8 b, f32x4 c) {
  return __builtin_amdgcn_mfma_f32_16x16x32_bf16(a, b, c, 0, 0, 0);
}

// ---------------- prep: transpose+convert weights, pack mask bits ----------
__global__ __launch_bounds__(256) void imha_prep(
    const float* __restrict__ Wq, const float* __restrict__ Wk,
    const float* __restrict__ Wo, const float* __restrict__ Wv,
    const int* __restrict__ mask,
    unsigned short* __restrict__ wqt, unsigned short* __restrict__ wkt,
    unsigned short* __restrict__ wot, unsigned short* __restrict__ wvt,
    unsigned* __restrict__ mb) {
  const int bx = blockIdx.x, t = threadIdx.x;
  if (bx < 2048) {
    const float* src = (bx < 1024) ? Wq : Wk;
    unsigned short* dst = (bx < 1024) ? wqt : wkt;
    const int tile = bx & 1023;
    const int ty = tile >> 5, tx = tile & 31;
    __shared__ float T[32][33];
    const int r = t >> 3, c4 = (t & 7) * 4;
    const float4 v = *(const float4*)&src[(ty * 32 + r) * 1024 + tx * 32 + c4];
    T[r][c4 + 0] = v.x; T[r][c4 + 1] = v.y; T[r][c4 + 2] = v.z; T[r][c4 + 3] = v.w;
    __syncthreads();
    ushort4 o;
    o.x = f2bf(T[c4 + 0][r]); o.y = f2bf(T[c4 + 1][r]);
    o.z = f2bf(T[c4 + 2][r]); o.w = f2bf(T[c4 + 3][r]);
    *(ushort4*)&dst[(tx * 32 + r) * 1024 + ty * 32 + c4] = o;
  } else if (bx < 2304) {
    const int idx = (bx - 2048) * 256 + t;
    const int n = idx >> 6, k = idx & 63;
    wot[idx] = f2bf(Wo[k * 1024 + n]);
  } else if (bx < 2816) {
    const int widx = (bx - 2304) * 256 + t;  // 131072 words
    const int qr = widx >> 6, wd = widx & 63;
    const int* mrow = mask + qr * 2048 + wd * 32;
    unsigned wv = 0;
    #pragma unroll
    for (int j4 = 0; j4 < 8; ++j4) {
      const int4 m4 = *(const int4*)&mrow[j4 * 4];
      wv |= (unsigned)(m4.x & 1) << (j4 * 4);
      wv |= (unsigned)(m4.y & 1) << (j4 * 4 + 1);
      wv |= (unsigned)(m4.z & 1) << (j4 * 4 + 2);
      wv |= (unsigned)(m4.w & 1) << (j4 * 4 + 3);
    }
    mb[widx] = wv;
  } else {
    const int widx = (bx - 2816) * 256 + t;  // 65536
    const int k = widx >> 6, n = widx & 63;
    wvt[n * 1024 + k] = f2bf(Wv[widx]);
  }
}

// ---------------- projection GEMM (BM=64, BN=128) --------------------------
__global__ __launch_bounds__(256) void imha_proj(
    const float* __restrict__ X, const unsigned short* __restrict__ Wt,
    const float* __restrict__ bias, unsigned short* __restrict__ dst,
    float preScale) {
  __shared__ unsigned short As[64][40];
  __shared__ unsigned short Bs[128][40];
  const int t = threadIdx.x, l = t & 63, w = t >> 6, lr = l & 15, lg = l >> 4;
  const int m0 = blockIdx.x * 64, n0 = blockIdx.y * 128;
  const int wr = w >> 1, wc = w & 1;
  const f32x4 zf = {0.f, 0.f, 0.f, 0.f};
  f32x4 acc[2][4];
  #pragma unroll
  for (int i = 0; i < 2; ++i)
    #pragma unroll
    for (int j = 0; j < 4; ++j) acc[i][j] = zf;

  for (int kk = 0; kk < 32; ++kk) {
    {
      const int rA = t >> 2, cA = (t & 3) * 8;
      const float4 v0 = *(const float4*)&X[(m0 + rA) * 1024 + kk * 32 + cA];
      const float4 v1 = *(const float4*)&X[(m0 + rA) * 1024 + kk * 32 + cA + 4];
      ushort4 o0, o1;
      o0.x = f2bf(v0.x); o0.y = f2bf(v0.y); o0.z = f2bf(v0.z); o0.w = f2bf(v0.w);
      o1.x = f2bf(v1.x); o1.y = f2bf(v1.y); o1.z = f2bf(v1.z); o1.w = f2bf(v1.w);
      *(ushort4*)&As[rA][cA] = o0;
      *(ushort4*)&As[rA][cA + 4] = o1;
      const int rB = t >> 2, cB = (t & 3) * 8;
      #pragma unroll
      for (int p = 0; p < 2; ++p) {
        const uint4 u = *(const uint4*)&Wt[(n0 + p * 64 + rB) * 1024 + kk * 32 + cB];
        *(uint4*)&Bs[p * 64 + rB][cB] = u;
      }
    }
    __syncthreads();
    bf16x8 a[2], bf[4];
    #pragma unroll
    for (int i = 0; i < 2; ++i) a[i] = load8(&As[wr * 32 + i * 16 + lr][lg * 8]);
    #pragma unroll
    for (int j = 0; j < 4; ++j) bf[j] = load8(&Bs[wc * 64 + j * 16 + lr][lg * 8]);
    #pragma unroll
    for (int i = 0; i < 2; ++i)
      #pragma unroll
      for (int j = 0; j < 4; ++j) acc[i][j] = mfma16(a[i], bf[j], acc[i][j]);
    __syncthreads();
  }
  #pragma unroll
  for (int j = 0; j < 4; ++j) {
    const int gn = n0 + wc * 64 + j * 16 + lr;
    const float bv = bias[gn];
    const int h = gn >> 6, d = gn & 63;
    #pragma unroll
    for (int i = 0; i < 2; ++i) {
      #pragma unroll
      for (int r = 0; r < 4; ++r) {
        const int gm = m0 + wr * 32 + i * 16 + lg * 4 + r;
        const int b = gm >> 11, s = gm & 2047;
        dst[(((b * 16 + h) * 2048 + s) << 6) + d] = f2bf((acc[i][j][r] + bv) * preScale);
      }
    }
  }
}

// ---------------- V projection (MFMA, K-split): partials -------------------
__global__ __launch_bounds__(256) void imha_vproj_mm(
    const float* __restrict__ V, const unsigned short* __restrict__ wvt,
    float* __restrict__ ctxvp) {
  const int t = threadIdx.x, l = t & 63, w = t >> 6, lr = l & 15, lg = l >> 4;
  const int m0 = blockIdx.x * 64 + w * 16;
  const int k0 = blockIdx.y * 128;
  const f32x4 zf = {0.f, 0.f, 0.f, 0.f};
  f32x4 acc[4];
  #pragma unroll
  for (int j = 0; j < 4; ++j) acc[j] = zf;
  #pragma unroll
  for (int kk = 0; kk < 4; ++kk) {
    const int kb = k0 + kk * 32 + lg * 8;
    const float4 v0 = *(const float4*)&V[(m0 + lr) * 1024 + kb];
    const float4 v1 = *(const float4*)&V[(m0 + lr) * 1024 + kb + 4];
    union { bf16x8 v; unsigned short u[8]; } au;
    au.u[0] = f2bf(v0.x); au.u[1] = f2bf(v0.y); au.u[2] = f2bf(v0.z); au.u[3] = f2bf(v0.w);
    au.u[4] = f2bf(v1.x); au.u[5] = f2bf(v1.y); au.u[6] = f2bf(v1.z); au.u[7] = f2bf(v1.w);
    #pragma unroll
    for (int j = 0; j < 4; ++j) {
      const bf16x8 bfr = load8(&wvt[(j * 16 + lr) * 1024 + kb]);
      acc[j] = mfma16(au.v, bfr, acc[j]);
    }
  }
  #pragma unroll
  for (int j = 0; j < 4; ++j)
    #pragma unroll
    for (int reg = 0; reg < 4; ++reg) {
      const int m = m0 + lg * 4 + reg;
      ctxvp[((size_t)blockIdx.y * 4096 + m) * 64 + j * 16 + lr] = acc[j][reg];
    }
}

// ---------------- reduce partials -> vpT[b,d,s] bf16 -----------------------
__global__ __launch_bounds__(256) void imha_vred(
    const float* __restrict__ ctxvp, const float* __restrict__ bv,
    unsigned short* __restrict__ vpt) {
  __shared__ float T[128][65];
  const int t = threadIdx.x;
  const int m0 = blockIdx.x * 128;  // 32 blocks
  #pragma unroll
  for (int i = 0; i < 32; ++i) {
    const int e = t + i * 256;
    float s = 0.f;
    #pragma unroll
    for (int p = 0; p < 8; ++p) s += ctxvp[(size_t)p * 262144 + (size_t)m0 * 64 + e];
    T[e >> 6][e & 63] = s;
  }
  __syncthreads();
  const int d = t >> 2, sc = (t & 3) * 32;
  const int b = m0 >> 11, srow = m0 & 2047;
  const float bias = bv[d];
  unsigned short* dst = vpt + ((size_t)b * 64 + d) * 2048 + srow + sc;
  #pragma unroll
  for (int i = 0; i < 32; i += 8) {
    ushort4 o0, o1;
    o0.x = f2bf(T[sc + i + 0][d] + bias); o0.y = f2bf(T[sc + i + 1][d] + bias);
    o0.z = f2bf(T[sc + i + 2][d] + bias); o0.w = f2bf(T[sc + i + 3][d] + bias);
    o1.x = f2bf(T[sc + i + 4][d] + bias); o1.y = f2bf(T[sc + i + 5][d] + bias);
    o1.z = f2bf(T[sc + i + 6][d] + bias); o1.w = f2bf(T[sc + i + 7][d] + bias);
    *(ushort4*)(dst + i) = o0;
    *(ushort4*)(dst + i + 4) = o1;
  }
}

// ---------------- pass1 (h-major): per-head exp2 row-partials --------------
// 512 blocks (XCD-swizzled): block = (q-tile 128, b*16+h); streams 16 K-tiles
// of 128 rows through dbuf LDS. Q hoisted. No shfl: 16 lane-partials per row.
__global__ __launch_bounds__(256, 3) void imha_pass1(
    const unsigned short* __restrict__ qhb, const unsigned short* __restrict__ khb,
    const unsigned* __restrict__ mb, float* __restrict__ lpart16) {
  __shared__ unsigned short Kb[2][8192];  // 2 x 128x64 bf16, XOR-swizzled
  const int t = threadIdx.x, l = t & 63, w = t >> 6, lr = l & 15, lg = l >> 4;
  const int orig = blockIdx.x;                       // 512
  const int swz = (orig & 7) * 64 + (orig >> 3);     // XCD-chunked
  const int q0 = (swz & 15) * 128, bh = swz >> 4;
  const int qw = q0 + w * 32;
  // hoisted Q fragments
  const unsigned short* qb = qhb + ((size_t)(bh * 2048 + qw) << 6);
  bf16x8 aq[2][2];
  #pragma unroll
  for (int rf = 0; rf < 2; ++rf)
    #pragma unroll
    for (int k2 = 0; k2 < 2; ++k2)
      aq[rf][k2] = load8(qb + (((rf * 16 + lr) << 6) + k2 * 32 + lg * 8));
  const unsigned short* kbase = khb + ((size_t)bh << 17);  // bh*2048*64
  uint4 pre[4];
  #pragma unroll
  for (int it = 0; it < 4; ++it)
    pre[it] = *(const uint4*)((const char*)kbase + (it * 256 + t) * 16);
  #pragma unroll
  for (int it = 0; it < 4; ++it) {
    const int off = (it * 256 + t) * 16, row = off >> 7, col = off & 127;
    *(uint4*)((char*)&Kb[0][0] + row * 128 + (col ^ ((row & 7) << 4))) = pre[it];
  }
  __syncthreads();
  float lsum[2][4] = {0.f, 0.f, 0.f, 0.f, 0.f, 0.f, 0.f, 0.f};
  #pragma unroll 1
  for (int kt = 0; kt < 16; ++kt) {
    if (kt < 15) {
      const char* nk = (const char*)kbase + (kt + 1) * 16384;
      #pragma unroll
      for (int it = 0; it < 4; ++it)
        pre[it] = *(const uint4*)(nk + (it * 256 + t) * 16);
    }
    // mask words for this k-tile: 128 bits per owned q-row
    uint4 mw[2][4];
    #pragma unroll
    for (int rf = 0; rf < 2; ++rf)
      #pragma unroll
      for (int reg = 0; reg < 4; ++reg) {
        const int qrow = qw + rf * 16 + lg * 4 + reg;
        mw[rf][reg] = *(const uint4*)&mb[qrow * 64 + kt * 4];
      }
    const char* kl = (const char*)&Kb[kt & 1][0];
    const int sxor = (lr & 7) << 4;
    __builtin_amdgcn_s_setprio(1);
    #pragma unroll
    for (int cf = 0; cf < 8; ++cf) {
      const int row = cf * 16 + lr;
      const bf16x8 b0 = load8((const unsigned short*)(kl + row * 128 + ((lg * 16) ^ sxor)));
      const bf16x8 b1 = load8((const unsigned short*)(kl + row * 128 + ((64 + lg * 16) ^ sxor)));
      #pragma unroll
      for (int rf = 0; rf < 2; ++rf) {
        f32x4 aini;
        #pragma unroll
        for (int reg = 0; reg < 4; ++reg) {
          const unsigned word = ((const unsigned*)&mw[rf][reg])[cf >> 1];
          const unsigned bit = (word >> (((cf & 1) << 4) + lr)) & 1u;
          aini[reg] = bit ? -30000.0f : 0.0f;
        }
        f32x4 acc = mfma16(aq[rf][0], b0, aini);
        acc = mfma16(aq[rf][1], b1, acc);
        #pragma unroll
        for (int reg = 0; reg < 4; ++reg)
          lsum[rf][reg] += __builtin_exp2f(acc[reg]);
      }
    }
    __builtin_amdgcn_s_setprio(0);
    if (kt < 15) {
      #pragma unroll
      for (int it = 0; it < 4; ++it) {
        const int off = (it * 256 + t) * 16, row = off >> 7, col = off & 127;
        *(uint4*)((char*)&Kb[(kt + 1) & 1][0] + row * 128 + (col ^ ((row & 7) << 4))) = pre[it];
      }
      __syncthreads();
    }
  }
  // unreduced 16-lane partials: lpart16[(bh*2048+q)*16 + lr]
  #pragma unroll
  for (int rf = 0; rf < 2; ++rf)
    #pragma unroll
    for (int reg = 0; reg < 4; ++reg) {
      const int qrow = bh * 2048 + qw + rf * 16 + lg * 4 + reg;
      lpart16[(qrow << 4) + lr] = lsum[rf][reg];
    }
}

// ---------------- linv = (1/16) / sum(lpart16) -----------------------------
__global__ __launch_bounds__(256) void imha_linv(
    const float* __restrict__ lpart16, float* __restrict__ linv) {
  const int i = blockIdx.x * 256 + threadIdx.x;  // 65536
  const float4* p = (const float4*)&lpart16[i << 4];
  float s = 0.f;
  #pragma unroll
  for (int j = 0; j < 4; ++j) {
    const float4 v = p[j];
    s += v.x + v.y + v.z + v.w;
  }
  linv[i] = 0.0625f / s;
}

// ---------------- pass2: attn_mean + partial ctx (K in LDS) ----------------
// 512 blocks (XCD-swizzled): q-tile 128 (4 waves x 32q), k-tile 128, h-loop 16
__global__ __launch_bounds__(256, 2) void imha_pass2(
    const unsigned short* __restrict__ qhb, const unsigned short* __restrict__ khb,
    const unsigned short* __restrict__ vpt, const unsigned* __restrict__ mb,
    const float* __restrict__ linv, float* __restrict__ attn_out,
    float* __restrict__ ctxp) {
  __shared__ unsigned short Ps[128][136];
  __shared__ unsigned short Kb[2][8192];
  const int t = threadIdx.x, l = t & 63, w = t >> 6, lr = l & 15, lg = l >> 4;
  const int orig = blockIdx.x;                    // 512
  const int swz = (orig & 7) * 64 + (orig >> 3);  // XCD-chunked
  const int q0 = (swz & 15) * 128, ksb = (swz >> 4) & 15, b = swz >> 8;
  const int k00 = ksb * 128;
  const int qw = q0 + w * 32;
  f32x4 aini[2][2][4];
  #pragma unroll
  for (int rf = 0; rf < 2; ++rf)
    #pragma unroll
    for (int reg = 0; reg < 4; ++reg) {
      const int qrow = qw + rf * 16 + lg * 4 + reg;
      const unsigned* mrow = mb + qrow * 64;
      #pragma unroll
      for (int kt = 0; kt < 2; ++kt)
        #pragma unroll
        for (int cf = 0; cf < 4; ++cf) {
          const unsigned word = mrow[(k00 + kt * 64 + cf * 16) >> 5];
          const unsigned bit = (word >> (((cf & 1) << 4) + lr)) & 1u;
          aini[rf][kt][cf][reg] = bit ? -30000.0f : 0.0f;
        }
    }
  float pm[2][2][4][4];
  #pragma unroll
  for (int a = 0; a < 2; ++a)
    #pragma unroll
    for (int c = 0; c < 2; ++c)
      #pragma unroll
      for (int d2 = 0; d2 < 4; ++d2)
        #pragma unroll
        for (int e = 0; e < 4; ++e) pm[a][c][d2][e] = 0.f;

  const unsigned short* kbase = khb + ((size_t)((b * 16) * 2048 + k00) << 6);
  uint4 pre[4];
  #pragma unroll
  for (int it = 0; it < 4; ++it)
    pre[it] = *(const uint4*)((const char*)kbase + (it * 256 + t) * 16);
  #pragma unroll
  for (int it = 0; it < 4; ++it) {
    const int off = (it * 256 + t) * 16, row = off >> 7, col = off & 127;
    *(uint4*)((char*)&Kb[0][0] + row * 128 + (col ^ ((row & 7) << 4))) = pre[it];
  }
  __syncthreads();
  #pragma unroll 1
  for (int h = 0; h < 16; ++h) {
    if (h < 15) {
      const char* nk = (const char*)(kbase + ((size_t)(h + 1) << 17));
      #pragma unroll
      for (int it = 0; it < 4; ++it)
        pre[it] = *(const uint4*)(nk + (it * 256 + t) * 16);
    }
    const unsigned short* qb = qhb + ((size_t)((b * 16 + h) * 2048 + qw) << 6);
    bf16x8 aq[2][2];
    #pragma unroll
    for (int rf = 0; rf < 2; ++rf)
      #pragma unroll
      for (int k2 = 0; k2 < 2; ++k2)
        aq[rf][k2] = load8(qb + (((rf * 16 + lr) << 6) + k2 * 32 + lg * 8));
    float4 li4[2];
    #pragma unroll
    for (int rf = 0; rf < 2; ++rf)
      li4[rf] = *(const float4*)&linv[(b * 16 + h) * 2048 + qw + rf * 16 + lg * 4];
    const char* kl = (const char*)&Kb[h & 1][0];
    const int sxor = (lr & 7) << 4;
    __builtin_amdgcn_s_setprio(1);
    #pragma unroll
    for (int kt = 0; kt < 2; ++kt) {
      #pragma unroll
      for (int cf = 0; cf < 4; ++cf) {
        const int row = kt * 64 + cf * 16 + lr;
        const bf16x8 b0 = load8((const unsigned short*)(kl + row * 128 + ((lg * 16) ^ sxor)));
        const bf16x8 b1 = load8((const unsigned short*)(kl + row * 128 + ((64 + lg * 16) ^ sxor)));
        #pragma unroll
        for (int rf = 0; rf < 2; ++rf) {
          f32x4 acc = mfma16(aq[rf][0], b0, aini[rf][kt][cf]);
          acc = mfma16(aq[rf][1], b1, acc);
          const float* lip = (const float*)&li4[rf];
          #pragma unroll
          for (int reg = 0; reg < 4; ++reg)
            pm[rf][kt][cf][reg] += __builtin_exp2f(acc[reg]) * lip[reg];
        }
      }
    }
    __builtin_amdgcn_s_setprio(0);
    if (h < 15) {
      #pragma unroll
      for (int it = 0; it < 4; ++it) {
        const int off = (it * 256 + t) * 16, row = off >> 7, col = off & 127;
        *(uint4*)((char*)&Kb[(h + 1) & 1][0] + row * 128 + (col ^ ((row & 7) << 4))) = pre[it];
      }
      __syncthreads();
    }
  }
  // write attn_mean (f32) + Ps (bf16)
  #pragma unroll
  for (int rf = 0; rf < 2; ++rf)
    #pragma unroll
    for (int kt = 0; kt < 2; ++kt)
      #pragma unroll
      for (int cf = 0; cf < 4; ++cf)
        #pragma unroll
        for (int reg = 0; reg < 4; ++reg) {
          const int qrow = qw + rf * 16 + lg * 4 + reg;
          const int col = k00 + kt * 64 + cf * 16 + lr;
          const float p = pm[rf][kt][cf][reg];
          attn_out[((size_t)(b * 2048 + qrow) << 11) + col] = p;
          Ps[w * 32 + rf * 16 + lg * 4 + reg][kt * 64 + cf * 16 + lr] = f2bf(p);
        }
  // PV: same-wave rows of Ps, V-frags from L2-resident vpt
  const f32x4 zf = {0.f, 0.f, 0.f, 0.f};
  f32x4 ctx[2][4];
  #pragma unroll
  for (int rf = 0; rf < 2; ++rf)
    #pragma unroll
    for (int dcf = 0; dcf < 4; ++dcf) ctx[rf][dcf] = zf;
  #pragma unroll
  for (int k2 = 0; k2 < 4; ++k2) {
    bf16x8 ap[2];
    #pragma unroll
    for (int rf = 0; rf < 2; ++rf)
      ap[rf] = load8(&Ps[w * 32 + rf * 16 + lr][k2 * 32 + lg * 8]);
    #pragma unroll
    for (int dcf = 0; dcf < 4; ++dcf) {
      const bf16x8 bvf = load8(vpt + ((size_t)(b * 64 + dcf * 16 + lr)) * 2048 + k00 + k2 * 32 + lg * 8);
      #pragma unroll
      for (int rf = 0; rf < 2; ++rf) ctx[rf][dcf] = mfma16(ap[rf], bvf, ctx[rf][dcf]);
    }
  }
  #pragma unroll
  for (int rf = 0; rf < 2; ++rf)
    #pragma unroll
    for (int dcf = 0; dcf < 4; ++dcf)
      #pragma unroll
      for (int reg = 0; reg < 4; ++reg) {
        const int m = b * 2048 + qw + rf * 16 + lg * 4 + reg;
        ctxp[((size_t)(ksb * 4096 + m) << 6) + dcf * 16 + lr] = ctx[rf][dcf][reg];
      }
}

// ---------------- ctx reduce: ctxr[m][d] bf16 = sum_ks ctxp ----------------
__global__ __launch_bounds__(256) void imha_ctxred(
    const float* __restrict__ ctxp, unsigned short* __restrict__ ctxr) {
  const int i4 = (blockIdx.x * 256 + threadIdx.x) * 4;  // 262144 elems
  float4 s = {0.f, 0.f, 0.f, 0.f};
  #pragma unroll
  for (int p = 0; p < 16; ++p) {
    const float4 v = *(const float4*)&ctxp[(size_t)p * 262144 + i4];
    s.x += v.x; s.y += v.y; s.z += v.z; s.w += v.w;
  }
  ushort4 o;
  o.x = f2bf(s.x); o.y = f2bf(s.y); o.z = f2bf(s.z); o.w = f2bf(s.w);
  *(ushort4*)&ctxr[i4] = o;
}

// ---------------- out projection: out = ctxr @ Wo + bo ---------------------
__global__ __launch_bounds__(256) void imha_outproj(
    const unsigned short* __restrict__ ctxr, const unsigned short* __restrict__ wot,
    const float* __restrict__ bo, float* __restrict__ out) {
  __shared__ unsigned short As[128][72];
  __shared__ unsigned short Bs[128][72];
  const int t = threadIdx.x, l = t & 63, w = t >> 6, lr = l & 15, lg = l >> 4;
  const int m0 = blockIdx.x * 128, n0 = blockIdx.y * 128;
  const int wr = w >> 1, wc = w & 1;
  {
    const int r = t >> 1, cs = (t & 1) * 32;
    #pragma unroll
    for (int i = 0; i < 4; ++i)
      *(uint4*)&As[r][cs + i * 8] = *(const uint4*)&ctxr[(m0 + r) * 64 + cs + i * 8];
    #pragma unroll
    for (int i = 0; i < 4; ++i)
      *(uint4*)&Bs[r][cs + i * 8] = *(const uint4*)&wot[(n0 + r) * 64 + cs + i * 8];
  }
  __syncthreads();
  const f32x4 zf = {0.f, 0.f, 0.f, 0.f};
  f32x4 acc[4][4];
  #pragma unroll
  for (int i = 0; i < 4; ++i)
    #pragma unroll
    for (int j = 0; j < 4; ++j) acc[i][j] = zf;
  #pragma unroll
  for (int k2 = 0; k2 < 2; ++k2) {
    bf16x8 a[4], bb[4];
    #pragma unroll
    for (int i = 0; i < 4; ++i) a[i] = load8(&As[wr * 64 + i * 16 + lr][k2 * 32 + lg * 8]);
    #pragma unroll
    for (int i = 0; i < 4; ++i) bb[i] = load8(&Bs[wc * 64 + i * 16 + lr][k2 * 32 + lg * 8]);
    #pragma unroll
    for (int i = 0; i < 4; ++i)
      #pragma unroll
      for (int j = 0; j < 4; ++j) acc[i][j] = mfma16(a[i], bb[j], acc[i][j]);
  }
  #pragma unroll
  for (int j = 0; j < 4; ++j) {
    const int gn = n0 + wc * 64 + j * 16 + lr;
    const float bv = bo[gn];
    #pragma unroll
    for (int i = 0; i < 4; ++i) {
      #pragma unroll
      for (int r = 0; r < 4; ++r) {
        const int gm = m0 + wr * 64 + i * 16 + lg * 4 + r;
        out[((size_t)gm << 10) + gn] = acc[i][j][r] + bv;
      }
    }
  }
}

// ---------------- host launch ----------------------------------------------
extern "C" void kernel_launch(void* const* d_in, const int* in_sizes, int n_in,
                              void* d_out, int out_size, void* d_ws, size_t ws_size,
                              hipStream_t stream) {
  const float* q  = (const float*)d_in[0];
  const float* k  = (const float*)d_in[1];
  const float* v  = (const float*)d_in[2];
  const int*  mask = (const int*)d_in[3];
  const float* Wq = (const float*)d_in[4];
  const float* bq = (const float*)d_in[5];
  const float* Wk = (const float*)d_in[6];
  const float* bk = (const float*)d_in[7];
  const float* Wv = (const float*)d_in[8];
  const float* bv = (const float*)d_in[9];
  const float* Wo = (const float*)d_in[10];
  const float* bo = (const float*)d_in[11];

  char* ws = (char*)d_ws;
  unsigned short* wqt  = (unsigned short*)(ws + 0);          // 2 MB
  unsigned short* wkt  = (unsigned short*)(ws + 2097152);    // 2 MB
  unsigned short* wot  = (unsigned short*)(ws + 4194304);    // 128 KB
  unsigned*       mb   = (unsigned*)      (ws + 4325376);    // 512 KB
  unsigned short* qhb  = (unsigned short*)(ws + 4849664);    // 8 MB
  unsigned short* khb  = (unsigned short*)(ws + 13238272);   // 8 MB
  unsigned short* vpt  = (unsigned short*)(ws + 21626880);   // 512 KB
  float*          linv = (float*)         (ws + 22151168);   // 256 KB
  float*          ctxp = (float*)         (ws + 22413312);   // 16 MB -> ends 39190528
  unsigned short* ctxr = (unsigned short*)(ws + 39190528);   // 512 KB -> ends 39702528
  // aliases inside ctxp region (dead at time of use):
  unsigned short* wvt  = (unsigned short*)(ws + 22413312);             // 128 KB, dead after vproj_mm
  float*          ctxvp= (float*)         (ws + 22413312 + 131072);    // 8 MB, dead after vred
  float*          lpart16 = (float*)      (ws + 22413312);             // 4 MB, dead before pass2

  float* out  = (float*)d_out;
  float* attn = out + (size_t)BB * SS * DD;  // 4,194,304

  const float qScale = 0.125f * 1.44269504088896340736f;  // fold log2(e) for exp2

  imha_prep<<<3072, 256, 0, stream>>>(Wq, Wk, Wo, Wv, mask, wqt, wkt, wot, wvt, mb);
  imha_vproj_mm<<<dim3(64, 8), 256, 0, stream>>>(v, wvt, ctxvp);
  imha_vred<<<32, 256, 0, stream>>>(ctxvp, bv, vpt);
  imha_proj<<<dim3(64, 8), 256, 0, stream>>>(q, wqt, bq, qhb, qScale);
  imha_proj<<<dim3(64, 8), 256, 0, stream>>>(k, wkt, bk, khb, 1.0f);
  imha_pass1<<<512, 256, 0, stream>>>(qhb, khb, mb, lpart16);
  imha_linv<<<256, 256, 0, stream>>>(lpart16, linv);
  imha_pass2<<<512, 256, 0, stream>>>(qhb, khb, vpt, mb, linv, attn, ctxp);
  imha_ctxred<<<256, 256, 0, stream>>>(ctxp, ctxr);
  imha_outproj<<<dim3(32, 8), 256, 0, stream>>>(ctxr, wot, bo, out);
}